// Round 5
// baseline (349.175 us; speedup 1.0000x reference)
//
#include <hip/hip_runtime.h>
#include <math.h>

// ---------------------------------------------------------------------------
// GCN: x1 = prelu(gcnconv(X, W1, b1)); x2 = prelu(gcnconv(x1, W2, b2));
//      out = elu(x2 @ P1 + pb1) @ P2 + pb2
// n = 50000, E = 800000, channels 128 -> 128 -> 64 -> (64 -> 64)
// R1: scatter-atomics -> CSR gather (2266 -> 445 us).
// R2: proj head latency-bound -> 2-phase LDS GEMM (445 -> 385 us).
// R3: GEMMs occupancy/ILP-bound -> register-blocked 64xM tile (385 -> 345 us).
// R4: gather_agg was MLP-bound (1 outstanding gather/wave, runtime-bound
//     loop). 8x unroll w/ 8 independent accumulators -> 8 loads in flight.
// ---------------------------------------------------------------------------

__global__ void zero_int_kernel(int* __restrict__ p, int n) {
  int i = blockIdx.x * blockDim.x + threadIdx.x;
  if (i < n) p[i] = 0;
}

__global__ void count_kernel(const int* __restrict__ dst, int* __restrict__ cnt, int E) {
  int e = blockIdx.x * blockDim.x + threadIdx.x;
  if (e < E) atomicAdd(&cnt[dst[e]], 1);
}

// dinv[i] = rsqrt(cnt[i] + 1)  (+1 = self-loop)
__global__ void dinv_kernel(const int* __restrict__ cnt, float* __restrict__ dinv, int n) {
  int i = blockIdx.x * blockDim.x + threadIdx.x;
  if (i < n) dinv[i] = rsqrtf((float)(cnt[i] + 1));
}

// in-place exclusive scan of off[0..n), off[n] = total. Single block, 1024 thr.
__global__ __launch_bounds__(1024) void scan_kernel(int* __restrict__ off, int n) {
  __shared__ int wsum[16];
  int tid = threadIdx.x;
  int lane = tid & 63, wid = tid >> 6;
  int running = 0;
  for (int base = 0; base < n; base += 1024) {
    int i = base + tid;
    int orig = (i < n) ? off[i] : 0;
    int v = orig;
    #pragma unroll
    for (int d = 1; d < 64; d <<= 1) {
      int t = __shfl_up(v, d);
      if (lane >= d) v += t;
    }
    if (lane == 63) wsum[wid] = v;
    __syncthreads();
    if (wid == 0) {
      int s = (lane < 16) ? wsum[lane] : 0;
      #pragma unroll
      for (int d = 1; d < 16; d <<= 1) {
        int t = __shfl_up(s, d);
        if (lane >= d) s += t;
      }
      if (lane < 16) wsum[lane] = s;
    }
    __syncthreads();
    int wprev = (wid == 0) ? 0 : wsum[wid - 1];
    if (i < n) off[i] = running + wprev + (v - orig);  // exclusive
    int total = wsum[15];
    __syncthreads();  // protect wsum before next chunk
    running += total;
  }
  if (tid == 0) off[n] = running;
}

__global__ void scatter_kernel(const int* __restrict__ src, const int* __restrict__ dst,
                               const int* __restrict__ off, int* __restrict__ cursor,
                               int* __restrict__ ssrc, int E) {
  int e = blockIdx.x * blockDim.x + threadIdx.x;
  if (e < E) {
    int d = dst[e];
    int pos = off[d] + atomicAdd(&cursor[d], 1);
    ssrc[pos] = src[e];
  }
}

// A [n,128] @ W [128,M] -> out [n,M], register-blocked.
// Block 256 thr: 64 rows x M cols; thread = 4 rows x (M/16) cols microtile.
template<int M>
__global__ __launch_bounds__(256) void gemm_rb_kernel(
    const float* __restrict__ A, const float* __restrict__ W,
    float* __restrict__ out, int n) {
  constexpr int MF4  = M / 4;    // float4 per W row
  constexpr int CPT4 = M / 64;   // float4 cols per thread (2 for 128, 1 for 64)
  constexpr int XP   = 33;
  __shared__ float Xs[64 * XP];
  __shared__ float Ws[32 * M];

  int tid = threadIdx.x;
  int tc = tid & 15;
  int tr = tid >> 4;
  int row0 = blockIdx.x * 64;

  float4 acc[4][CPT4];
  #pragma unroll
  for (int j = 0; j < 4; ++j)
    #pragma unroll
    for (int q = 0; q < CPT4; ++q) acc[j][q] = make_float4(0.f, 0.f, 0.f, 0.f);

  const float4* A4 = (const float4*)A;
  const float4* W4 = (const float4*)W;
  float4* Ws4 = (float4*)Ws;

  for (int c = 0; c < 4; ++c) {       // K chunks of 32
    __syncthreads();                  // previous chunk fully consumed
    // stage X chunk: 64 rows x 8 float4
    #pragma unroll
    for (int i = 0; i < 2; ++i) {
      int idx = tid + i * 256;
      int r = idx >> 3, j4 = idx & 7;
      int row = row0 + r;
      float4 v = (row < n) ? A4[(size_t)row * 32 + c * 8 + j4]
                           : make_float4(0.f, 0.f, 0.f, 0.f);
      float* xp = &Xs[r * XP + j4 * 4];
      xp[0] = v.x; xp[1] = v.y; xp[2] = v.z; xp[3] = v.w;
    }
    // stage W chunk: 32 x MF4 float4, linear
    #pragma unroll
    for (int i = 0; i < 32 * MF4 / 256; ++i) {
      int idx = tid + i * 256;
      Ws4[idx] = W4[(size_t)c * 32 * MF4 + idx];
    }
    __syncthreads();
    #pragma unroll 4
    for (int k = 0; k < 32; ++k) {
      float xv[4];
      #pragma unroll
      for (int j = 0; j < 4; ++j) xv[j] = Xs[(tr * 4 + j) * XP + k];
      #pragma unroll
      for (int q = 0; q < CPT4; ++q) {
        float4 w = Ws4[k * MF4 + tc * CPT4 + q];
        #pragma unroll
        for (int j = 0; j < 4; ++j) {
          acc[j][q].x = fmaf(xv[j], w.x, acc[j][q].x);
          acc[j][q].y = fmaf(xv[j], w.y, acc[j][q].y);
          acc[j][q].z = fmaf(xv[j], w.z, acc[j][q].z);
          acc[j][q].w = fmaf(xv[j], w.w, acc[j][q].w);
        }
      }
    }
  }

  float4* out4 = (float4*)out;
  #pragma unroll
  for (int j = 0; j < 4; ++j) {
    int row = row0 + tr * 4 + j;
    if (row < n) {
      #pragma unroll
      for (int q = 0; q < CPT4; ++q)
        out4[(size_t)row * MF4 + tc * CPT4 + q] = acc[j][q];
    }
  }
}

// One wave per dst node: acc = self + sum_e h[src_e]*w_e; out = prelu(acc+b).
// 8x unrolled edge loop, 8 independent accumulators -> 8 gathers in flight.
// M = 128: lane owns float2; M = 64: lane owns 1 float.
template<int M>
__global__ __launch_bounds__(256) void gather_agg_kernel(
    const float* __restrict__ h, const int* __restrict__ off,
    const int* __restrict__ ssrc, const float* __restrict__ dinv,
    const float* __restrict__ bias, const float* __restrict__ a_ptr,
    float* __restrict__ out, int n) {
  int node = (blockIdx.x * blockDim.x + threadIdx.x) >> 6;
  int lane = threadIdx.x & 63;
  if (node >= n) return;
  float di = dinv[node];
  int beg = off[node], end = off[node + 1];
  float a = *a_ptr;

  if (M == 128) {
    const float2* h2 = (const float2*)h;
    float2 hv = h2[(size_t)node * 64 + lane];
    float sw = di * di;
    float2 acc[8];
    acc[0] = make_float2(hv.x * sw, hv.y * sw);
    #pragma unroll
    for (int u = 1; u < 8; ++u) acc[u] = make_float2(0.f, 0.f);

    for (int i = beg; i < end; i += 64) {
      int cnt = end - i; if (cnt > 64) cnt = 64;
      int sl = (lane < cnt) ? ssrc[i + lane] : 0;
      float wl = (lane < cnt) ? dinv[sl] * di : 0.f;
      int j = 0;
      for (; j + 8 <= cnt; j += 8) {
        int s[8]; float w[8]; float2 v[8];
        #pragma unroll
        for (int u = 0; u < 8; ++u) { s[u] = __shfl(sl, j + u); w[u] = __shfl(wl, j + u); }
        #pragma unroll
        for (int u = 0; u < 8; ++u) v[u] = h2[(size_t)s[u] * 64 + lane];
        #pragma unroll
        for (int u = 0; u < 8; ++u) {
          acc[u].x = fmaf(v[u].x, w[u], acc[u].x);
          acc[u].y = fmaf(v[u].y, w[u], acc[u].y);
        }
      }
      for (; j < cnt; ++j) {
        int s = __shfl(sl, j);
        float w = __shfl(wl, j);
        float2 v = h2[(size_t)s * 64 + lane];
        acc[j & 7].x = fmaf(v.x, w, acc[j & 7].x);
        acc[j & 7].y = fmaf(v.y, w, acc[j & 7].y);
      }
    }
    #pragma unroll
    for (int u = 4; u > 0; u >>= 1)
      #pragma unroll
      for (int q = 0; q < u; ++q) {
        acc[q].x += acc[q + u].x; acc[q].y += acc[q + u].y;
      }
    float x = acc[0].x + bias[2 * lane], y = acc[0].y + bias[2 * lane + 1];
    x = x >= 0.f ? x : a * x;
    y = y >= 0.f ? y : a * y;
    ((float2*)out)[(size_t)node * 64 + lane] = make_float2(x, y);
  } else {
    float acc[8];
    acc[0] = h[(size_t)node * 64 + lane] * di * di;
    #pragma unroll
    for (int u = 1; u < 8; ++u) acc[u] = 0.f;

    for (int i = beg; i < end; i += 64) {
      int cnt = end - i; if (cnt > 64) cnt = 64;
      int sl = (lane < cnt) ? ssrc[i + lane] : 0;
      float wl = (lane < cnt) ? dinv[sl] * di : 0.f;
      int j = 0;
      for (; j + 8 <= cnt; j += 8) {
        int s[8]; float w[8]; float v[8];
        #pragma unroll
        for (int u = 0; u < 8; ++u) { s[u] = __shfl(sl, j + u); w[u] = __shfl(wl, j + u); }
        #pragma unroll
        for (int u = 0; u < 8; ++u) v[u] = h[(size_t)s[u] * 64 + lane];
        #pragma unroll
        for (int u = 0; u < 8; ++u) acc[u] = fmaf(v[u], w[u], acc[u]);
      }
      for (; j < cnt; ++j) {
        int s = __shfl(sl, j);
        float w = __shfl(wl, j);
        acc[j & 7] = fmaf(h[(size_t)s * 64 + lane], w, acc[j & 7]);
      }
    }
    #pragma unroll
    for (int u = 4; u > 0; u >>= 1)
      #pragma unroll
      for (int q = 0; q < u; ++q) acc[q] += acc[q + u];
    float x = acc[0] + bias[lane];
    out[(size_t)node * 64 + lane] = x >= 0.f ? x : a * x;
  }
}

// Projection head: out = elu(x @ P1 + pb1) @ P2 + pb2.
// Block = 256 threads = 16 nodes x 16 colgroups; float4 acc per thread (ILP=4).
__global__ __launch_bounds__(256) void proj_head_kernel(
    const float* __restrict__ x, const float* __restrict__ P1,
    const float* __restrict__ pb1, const float* __restrict__ P2,
    const float* __restrict__ pb2, float* __restrict__ out, int n) {
  __shared__ float P1s[64 * 64];
  __shared__ float P2s[64 * 64];
  __shared__ float Xs[16 * 64];   // x rows, then reused for h rows
  __shared__ float b1s[64];
  __shared__ float b2s[64];
  int tid = threadIdx.x;

  float4* P1s4 = (float4*)P1s;
  float4* P2s4 = (float4*)P2s;
  const float4* P1g = (const float4*)P1;
  const float4* P2g = (const float4*)P2;
  #pragma unroll
  for (int i = 0; i < 4; ++i) {
    P1s4[tid + 256 * i] = P1g[tid + 256 * i];
    P2s4[tid + 256 * i] = P2g[tid + 256 * i];
  }
  if (tid < 64) { b1s[tid] = pb1[tid]; b2s[tid] = pb2[tid]; }

  int row0 = blockIdx.x * 16;
  int nrows = n - row0; if (nrows > 16) nrows = 16;
  const float4* X4 = (const float4*)(x + (size_t)row0 * 64);
  if (tid < nrows * 16) ((float4*)Xs)[tid] = X4[tid];
  __syncthreads();

  int cg = tid & 15;
  int r  = tid >> 4;
  bool active = (r < nrows);

  // phase 1: h = elu(x @ P1 + pb1)
  float4 acc = active ? ((const float4*)b1s)[cg] : make_float4(0, 0, 0, 0);
  if (active) {
    const float* xrow = Xs + r * 64;
    #pragma unroll 8
    for (int k = 0; k < 64; ++k) {
      float xv = xrow[k];
      float4 w = P1s4[k * 16 + cg];
      acc.x = fmaf(xv, w.x, acc.x);
      acc.y = fmaf(xv, w.y, acc.y);
      acc.z = fmaf(xv, w.z, acc.z);
      acc.w = fmaf(xv, w.w, acc.w);
    }
    acc.x = acc.x > 0.f ? acc.x : expm1f(acc.x);
    acc.y = acc.y > 0.f ? acc.y : expm1f(acc.y);
    acc.z = acc.z > 0.f ? acc.z : expm1f(acc.z);
    acc.w = acc.w > 0.f ? acc.w : expm1f(acc.w);
  }
  __syncthreads();               // everyone done reading Xs
  if (active) ((float4*)Xs)[r * 16 + cg] = acc;   // Xs now holds h
  __syncthreads();

  // phase 2: out = h @ P2 + pb2
  if (!active) return;
  float4 o = ((const float4*)b2s)[cg];
  const float* hrow = Xs + r * 64;
  #pragma unroll 8
  for (int k = 0; k < 64; ++k) {
    float hv = hrow[k];
    float4 w = P2s4[k * 16 + cg];
    o.x = fmaf(hv, w.x, o.x);
    o.y = fmaf(hv, w.y, o.y);
    o.z = fmaf(hv, w.z, o.z);
    o.w = fmaf(hv, w.w, o.w);
  }
  ((float4*)(out + (size_t)(row0 + r) * 64))[cg] = o;
}

extern "C" void kernel_launch(void* const* d_in, const int* in_sizes, int n_in,
                              void* d_out, int out_size, void* d_ws, size_t ws_size,
                              hipStream_t stream) {
  const float* X   = (const float*)d_in[0];
  const int*   EI  = (const int*)d_in[1];
  const float* W1  = (const float*)d_in[2];
  const float* b1  = (const float*)d_in[3];
  const float* W2  = (const float*)d_in[4];
  const float* b2  = (const float*)d_in[5];
  const float* pa  = (const float*)d_in[6];
  const float* P1  = (const float*)d_in[7];
  const float* pb1 = (const float*)d_in[8];
  const float* P2  = (const float*)d_in[9];
  const float* pb2 = (const float*)d_in[10];
  float* out = (float*)d_out;

  int n = in_sizes[0] / 128;   // 50000
  int E = in_sizes[1] / 2;     // 800000
  const int* src = EI;
  const int* dst = EI + E;

  // workspace: dinv[n] f32 | off[n+1] i32 | cursor[n] i32 | ssrc[E] i32 |
  //            (pad to 16B) | bufA[n*128] f32 | bufB[n*128] f32
  float* ws   = (float*)d_ws;
  float* dinv = ws;
  int*   off    = (int*)(ws + n);
  int*   cursor = off + (n + 1);
  int*   ssrc   = cursor + n;
  size_t ofs = (size_t)n + (n + 1) + n + E;
  ofs = (ofs + 3) & ~(size_t)3;  // 16B-align the float4 buffers
  float* bufA = ws + ofs;
  float* bufB = bufA + (size_t)n * 128;
  float* h1 = bufA;
  float* x1 = bufB;
  float* h2 = bufA;
  float* x2 = bufA + (size_t)n * 64;

  const int B = 256;
  // CSR build: histogram (doubles as degree) -> dinv -> scan -> scatter
  zero_int_kernel<<<(2 * n + 1 + B - 1) / B, B, 0, stream>>>(off, 2 * n + 1);
  count_kernel<<<(E + B - 1) / B, B, 0, stream>>>(dst, off, E);
  dinv_kernel<<<(n + B - 1) / B, B, 0, stream>>>(off, dinv, n);
  scan_kernel<<<1, 1024, 0, stream>>>(off, n);
  scatter_kernel<<<(E + B - 1) / B, B, 0, stream>>>(src, dst, off, cursor, ssrc, E);

  // layer 1
  gemm_rb_kernel<128><<<(n + 63) / 64, 256, 0, stream>>>(X, W1, h1, n);
  gather_agg_kernel<128><<<(n * 64 + 255) / 256, 256, 0, stream>>>(
      h1, off, ssrc, dinv, b1, pa, x1, n);

  // layer 2
  gemm_rb_kernel<64><<<(n + 63) / 64, 256, 0, stream>>>(x1, W2, h2, n);
  gather_agg_kernel<64><<<(n * 64 + 255) / 256, 256, 0, stream>>>(
      h2, off, ssrc, dinv, b2, pa, x2, n);

  // projection head
  proj_head_kernel<<<(n + 15) / 16, 256, 0, stream>>>(x2, P1, pb1, P2, pb2, out, n);
}

// Round 6
// 312.912 us; speedup vs baseline: 1.1159x; 1.1159x over previous
//
#include <hip/hip_runtime.h>
#include <math.h>

// ---------------------------------------------------------------------------
// GCN: x1 = prelu(gcnconv(X, W1, b1)); x2 = prelu(gcnconv(x1, W2, b2));
//      out = elu(x2 @ P1 + pb1) @ P2 + pb2
// n = 50000, E = 800000, channels 128 -> 128 -> 64 -> (64 -> 64)
// R1: scatter-atomics -> CSR gather (2266 -> 445 us).
// R2: proj head latency-bound -> 2-phase LDS GEMM (445 -> 385 us).
// R3: GEMMs occupancy/ILP-bound -> register-blocked 64xM tile (385 -> 345 us).
// R4: 8x unroll REGRESSED: tail loop's acc[j&7] runtime index demoted acc[]
//     to LDS scratch (LDS 16KB, 2.6e7 bank conflicts).
// R5: MLP-8 with ALL-STATIC indexing: pad chunk count to multiple of 8
//     (padded lanes have w=0), no tail loop -> acc stays in VGPRs.
// ---------------------------------------------------------------------------

__global__ void zero_int_kernel(int* __restrict__ p, int n) {
  int i = blockIdx.x * blockDim.x + threadIdx.x;
  if (i < n) p[i] = 0;
}

__global__ void count_kernel(const int* __restrict__ dst, int* __restrict__ cnt, int E) {
  int e = blockIdx.x * blockDim.x + threadIdx.x;
  if (e < E) atomicAdd(&cnt[dst[e]], 1);
}

// dinv[i] = rsqrt(cnt[i] + 1)  (+1 = self-loop)
__global__ void dinv_kernel(const int* __restrict__ cnt, float* __restrict__ dinv, int n) {
  int i = blockIdx.x * blockDim.x + threadIdx.x;
  if (i < n) dinv[i] = rsqrtf((float)(cnt[i] + 1));
}

// in-place exclusive scan of off[0..n), off[n] = total. Single block, 1024 thr.
__global__ __launch_bounds__(1024) void scan_kernel(int* __restrict__ off, int n) {
  __shared__ int wsum[16];
  int tid = threadIdx.x;
  int lane = tid & 63, wid = tid >> 6;
  int running = 0;
  for (int base = 0; base < n; base += 1024) {
    int i = base + tid;
    int orig = (i < n) ? off[i] : 0;
    int v = orig;
    #pragma unroll
    for (int d = 1; d < 64; d <<= 1) {
      int t = __shfl_up(v, d);
      if (lane >= d) v += t;
    }
    if (lane == 63) wsum[wid] = v;
    __syncthreads();
    if (wid == 0) {
      int s = (lane < 16) ? wsum[lane] : 0;
      #pragma unroll
      for (int d = 1; d < 16; d <<= 1) {
        int t = __shfl_up(s, d);
        if (lane >= d) s += t;
      }
      if (lane < 16) wsum[lane] = s;
    }
    __syncthreads();
    int wprev = (wid == 0) ? 0 : wsum[wid - 1];
    if (i < n) off[i] = running + wprev + (v - orig);  // exclusive
    int total = wsum[15];
    __syncthreads();  // protect wsum before next chunk
    running += total;
  }
  if (tid == 0) off[n] = running;
}

__global__ void scatter_kernel(const int* __restrict__ src, const int* __restrict__ dst,
                               const int* __restrict__ off, int* __restrict__ cursor,
                               int* __restrict__ ssrc, int E) {
  int e = blockIdx.x * blockDim.x + threadIdx.x;
  if (e < E) {
    int d = dst[e];
    int pos = off[d] + atomicAdd(&cursor[d], 1);
    ssrc[pos] = src[e];
  }
}

// A [n,128] @ W [128,M] -> out [n,M], register-blocked.
// Block 256 thr: 64 rows x M cols; thread = 4 rows x (M/16) cols microtile.
template<int M>
__global__ __launch_bounds__(256) void gemm_rb_kernel(
    const float* __restrict__ A, const float* __restrict__ W,
    float* __restrict__ out, int n) {
  constexpr int MF4  = M / 4;    // float4 per W row
  constexpr int CPT4 = M / 64;   // float4 cols per thread (2 for 128, 1 for 64)
  constexpr int XP   = 33;
  __shared__ float Xs[64 * XP];
  __shared__ float Ws[32 * M];

  int tid = threadIdx.x;
  int tc = tid & 15;
  int tr = tid >> 4;
  int row0 = blockIdx.x * 64;

  float4 acc[4][CPT4];
  #pragma unroll
  for (int j = 0; j < 4; ++j)
    #pragma unroll
    for (int q = 0; q < CPT4; ++q) acc[j][q] = make_float4(0.f, 0.f, 0.f, 0.f);

  const float4* A4 = (const float4*)A;
  const float4* W4 = (const float4*)W;
  float4* Ws4 = (float4*)Ws;

  for (int c = 0; c < 4; ++c) {       // K chunks of 32
    __syncthreads();                  // previous chunk fully consumed
    // stage X chunk: 64 rows x 8 float4
    #pragma unroll
    for (int i = 0; i < 2; ++i) {
      int idx = tid + i * 256;
      int r = idx >> 3, j4 = idx & 7;
      int row = row0 + r;
      float4 v = (row < n) ? A4[(size_t)row * 32 + c * 8 + j4]
                           : make_float4(0.f, 0.f, 0.f, 0.f);
      float* xp = &Xs[r * XP + j4 * 4];
      xp[0] = v.x; xp[1] = v.y; xp[2] = v.z; xp[3] = v.w;
    }
    // stage W chunk: 32 x MF4 float4, linear
    #pragma unroll
    for (int i = 0; i < 32 * MF4 / 256; ++i) {
      int idx = tid + i * 256;
      Ws4[idx] = W4[(size_t)c * 32 * MF4 + idx];
    }
    __syncthreads();
    #pragma unroll 4
    for (int k = 0; k < 32; ++k) {
      float xv[4];
      #pragma unroll
      for (int j = 0; j < 4; ++j) xv[j] = Xs[(tr * 4 + j) * XP + k];
      #pragma unroll
      for (int q = 0; q < CPT4; ++q) {
        float4 w = Ws4[k * MF4 + tc * CPT4 + q];
        #pragma unroll
        for (int j = 0; j < 4; ++j) {
          acc[j][q].x = fmaf(xv[j], w.x, acc[j][q].x);
          acc[j][q].y = fmaf(xv[j], w.y, acc[j][q].y);
          acc[j][q].z = fmaf(xv[j], w.z, acc[j][q].z);
          acc[j][q].w = fmaf(xv[j], w.w, acc[j][q].w);
        }
      }
    }
  }

  float4* out4 = (float4*)out;
  #pragma unroll
  for (int j = 0; j < 4; ++j) {
    int row = row0 + tr * 4 + j;
    if (row < n) {
      #pragma unroll
      for (int q = 0; q < CPT4; ++q)
        out4[(size_t)row * MF4 + tc * CPT4 + q] = acc[j][q];
    }
  }
}

// One wave per dst node: acc = self + sum_e h[src_e]*w_e; out = prelu(acc+b).
// MLP-8: chunk count padded to multiple of 8 (padded lanes carry w=0), so the
// 8-wide unroll has NO tail and all register-array indices are compile-time.
template<int M>
__global__ __launch_bounds__(256) void gather_agg_kernel(
    const float* __restrict__ h, const int* __restrict__ off,
    const int* __restrict__ ssrc, const float* __restrict__ dinv,
    const float* __restrict__ bias, const float* __restrict__ a_ptr,
    float* __restrict__ out, int n) {
  int node = (blockIdx.x * blockDim.x + threadIdx.x) >> 6;
  int lane = threadIdx.x & 63;
  if (node >= n) return;
  float di = dinv[node];
  int beg = off[node], end = off[node + 1];
  float a = *a_ptr;

  if (M == 128) {
    const float2* h2 = (const float2*)h;
    float2 hv = h2[(size_t)node * 64 + lane];
    float sw = di * di;
    float2 acc[8];
    acc[0] = make_float2(hv.x * sw, hv.y * sw);
    #pragma unroll
    for (int u = 1; u < 8; ++u) acc[u] = make_float2(0.f, 0.f);

    for (int i = beg; i < end; i += 64) {
      int cnt = end - i; if (cnt > 64) cnt = 64;
      int sl = (lane < cnt) ? ssrc[i + lane] : 0;
      float wl = (lane < cnt) ? dinv[sl] * di : 0.f;
      int cnt8 = (cnt + 7) & ~7;           // pad: lanes >= cnt have wl = 0
      for (int j = 0; j < cnt8; j += 8) {
        int s[8]; float w[8]; float2 v[8];
        #pragma unroll
        for (int u = 0; u < 8; ++u) { s[u] = __shfl(sl, j + u); w[u] = __shfl(wl, j + u); }
        #pragma unroll
        for (int u = 0; u < 8; ++u) v[u] = h2[(size_t)s[u] * 64 + lane];
        #pragma unroll
        for (int u = 0; u < 8; ++u) {
          acc[u].x = fmaf(v[u].x, w[u], acc[u].x);
          acc[u].y = fmaf(v[u].y, w[u], acc[u].y);
        }
      }
    }
    #pragma unroll
    for (int u = 4; u > 0; u >>= 1)
      #pragma unroll
      for (int q = 0; q < u; ++q) {
        acc[q].x += acc[q + u].x; acc[q].y += acc[q + u].y;
      }
    float x = acc[0].x + bias[2 * lane], y = acc[0].y + bias[2 * lane + 1];
    x = x >= 0.f ? x : a * x;
    y = y >= 0.f ? y : a * y;
    ((float2*)out)[(size_t)node * 64 + lane] = make_float2(x, y);
  } else {
    float acc[8];
    acc[0] = h[(size_t)node * 64 + lane] * di * di;
    #pragma unroll
    for (int u = 1; u < 8; ++u) acc[u] = 0.f;

    for (int i = beg; i < end; i += 64) {
      int cnt = end - i; if (cnt > 64) cnt = 64;
      int sl = (lane < cnt) ? ssrc[i + lane] : 0;
      float wl = (lane < cnt) ? dinv[sl] * di : 0.f;
      int cnt8 = (cnt + 7) & ~7;
      for (int j = 0; j < cnt8; j += 8) {
        int s[8]; float w[8]; float v[8];
        #pragma unroll
        for (int u = 0; u < 8; ++u) { s[u] = __shfl(sl, j + u); w[u] = __shfl(wl, j + u); }
        #pragma unroll
        for (int u = 0; u < 8; ++u) v[u] = h[(size_t)s[u] * 64 + lane];
        #pragma unroll
        for (int u = 0; u < 8; ++u) acc[u] = fmaf(v[u], w[u], acc[u]);
      }
    }
    #pragma unroll
    for (int u = 4; u > 0; u >>= 1)
      #pragma unroll
      for (int q = 0; q < u; ++q) acc[q] += acc[q + u];
    float x = acc[0] + bias[lane];
    out[(size_t)node * 64 + lane] = x >= 0.f ? x : a * x;
  }
}

// Projection head: out = elu(x @ P1 + pb1) @ P2 + pb2.
// Block = 256 threads = 16 nodes x 16 colgroups; float4 acc per thread (ILP=4).
__global__ __launch_bounds__(256) void proj_head_kernel(
    const float* __restrict__ x, const float* __restrict__ P1,
    const float* __restrict__ pb1, const float* __restrict__ P2,
    const float* __restrict__ pb2, float* __restrict__ out, int n) {
  __shared__ float P1s[64 * 64];
  __shared__ float P2s[64 * 64];
  __shared__ float Xs[16 * 64];   // x rows, then reused for h rows
  __shared__ float b1s[64];
  __shared__ float b2s[64];
  int tid = threadIdx.x;

  float4* P1s4 = (float4*)P1s;
  float4* P2s4 = (float4*)P2s;
  const float4* P1g = (const float4*)P1;
  const float4* P2g = (const float4*)P2;
  #pragma unroll
  for (int i = 0; i < 4; ++i) {
    P1s4[tid + 256 * i] = P1g[tid + 256 * i];
    P2s4[tid + 256 * i] = P2g[tid + 256 * i];
  }
  if (tid < 64) { b1s[tid] = pb1[tid]; b2s[tid] = pb2[tid]; }

  int row0 = blockIdx.x * 16;
  int nrows = n - row0; if (nrows > 16) nrows = 16;
  const float4* X4 = (const float4*)(x + (size_t)row0 * 64);
  if (tid < nrows * 16) ((float4*)Xs)[tid] = X4[tid];
  __syncthreads();

  int cg = tid & 15;
  int r  = tid >> 4;
  bool active = (r < nrows);

  // phase 1: h = elu(x @ P1 + pb1)
  float4 acc = active ? ((const float4*)b1s)[cg] : make_float4(0, 0, 0, 0);
  if (active) {
    const float* xrow = Xs + r * 64;
    #pragma unroll 8
    for (int k = 0; k < 64; ++k) {
      float xv = xrow[k];
      float4 w = P1s4[k * 16 + cg];
      acc.x = fmaf(xv, w.x, acc.x);
      acc.y = fmaf(xv, w.y, acc.y);
      acc.z = fmaf(xv, w.z, acc.z);
      acc.w = fmaf(xv, w.w, acc.w);
    }
    acc.x = acc.x > 0.f ? acc.x : expm1f(acc.x);
    acc.y = acc.y > 0.f ? acc.y : expm1f(acc.y);
    acc.z = acc.z > 0.f ? acc.z : expm1f(acc.z);
    acc.w = acc.w > 0.f ? acc.w : expm1f(acc.w);
  }
  __syncthreads();               // everyone done reading Xs
  if (active) ((float4*)Xs)[r * 16 + cg] = acc;   // Xs now holds h
  __syncthreads();

  // phase 2: out = h @ P2 + pb2
  if (!active) return;
  float4 o = ((const float4*)b2s)[cg];
  const float* hrow = Xs + r * 64;
  #pragma unroll 8
  for (int k = 0; k < 64; ++k) {
    float hv = hrow[k];
    float4 w = P2s4[k * 16 + cg];
    o.x = fmaf(hv, w.x, o.x);
    o.y = fmaf(hv, w.y, o.y);
    o.z = fmaf(hv, w.z, o.z);
    o.w = fmaf(hv, w.w, o.w);
  }
  ((float4*)(out + (size_t)(row0 + r) * 64))[cg] = o;
}

extern "C" void kernel_launch(void* const* d_in, const int* in_sizes, int n_in,
                              void* d_out, int out_size, void* d_ws, size_t ws_size,
                              hipStream_t stream) {
  const float* X   = (const float*)d_in[0];
  const int*   EI  = (const int*)d_in[1];
  const float* W1  = (const float*)d_in[2];
  const float* b1  = (const float*)d_in[3];
  const float* W2  = (const float*)d_in[4];
  const float* b2  = (const float*)d_in[5];
  const float* pa  = (const float*)d_in[6];
  const float* P1  = (const float*)d_in[7];
  const float* pb1 = (const float*)d_in[8];
  const float* P2  = (const float*)d_in[9];
  const float* pb2 = (const float*)d_in[10];
  float* out = (float*)d_out;

  int n = in_sizes[0] / 128;   // 50000
  int E = in_sizes[1] / 2;     // 800000
  const int* src = EI;
  const int* dst = EI + E;

  // workspace: dinv[n] f32 | off[n+1] i32 | cursor[n] i32 | ssrc[E] i32 |
  //            (pad to 16B) | bufA[n*128] f32 | bufB[n*128] f32
  float* ws   = (float*)d_ws;
  float* dinv = ws;
  int*   off    = (int*)(ws + n);
  int*   cursor = off + (n + 1);
  int*   ssrc   = cursor + n;
  size_t ofs = (size_t)n + (n + 1) + n + E;
  ofs = (ofs + 3) & ~(size_t)3;  // 16B-align the float4 buffers
  float* bufA = ws + ofs;
  float* bufB = bufA + (size_t)n * 128;
  float* h1 = bufA;
  float* x1 = bufB;
  float* h2 = bufA;
  float* x2 = bufA + (size_t)n * 64;

  const int B = 256;
  // CSR build: histogram (doubles as degree) -> dinv -> scan -> scatter
  zero_int_kernel<<<(2 * n + 1 + B - 1) / B, B, 0, stream>>>(off, 2 * n + 1);
  count_kernel<<<(E + B - 1) / B, B, 0, stream>>>(dst, off, E);
  dinv_kernel<<<(n + B - 1) / B, B, 0, stream>>>(off, dinv, n);
  scan_kernel<<<1, 1024, 0, stream>>>(off, n);
  scatter_kernel<<<(E + B - 1) / B, B, 0, stream>>>(src, dst, off, cursor, ssrc, E);

  // layer 1
  gemm_rb_kernel<128><<<(n + 63) / 64, 256, 0, stream>>>(X, W1, h1, n);
  gather_agg_kernel<128><<<(n * 64 + 255) / 256, 256, 0, stream>>>(
      h1, off, ssrc, dinv, b1, pa, x1, n);

  // layer 2
  gemm_rb_kernel<64><<<(n + 63) / 64, 256, 0, stream>>>(x1, W2, h2, n);
  gather_agg_kernel<64><<<(n * 64 + 255) / 256, 256, 0, stream>>>(
      h2, off, ssrc, dinv, b2, pa, x2, n);

  // projection head
  proj_head_kernel<<<(n + 15) / 16, 256, 0, stream>>>(x2, P1, pb1, P2, pb2, out, n);
}